// Round 1
// 169.548 us; speedup vs baseline: 1.0068x; 1.0068x over previous
//
#include <hip/hip_runtime.h>

#define BS 64
#define TT 2048
#define NJ 24
#define ROWF 99            // 24*4 quats + 3 pos
#define BLOCK 128
#define NROWS (BS * TT)    // 131072 rows, one thread per row

// 16B load at 4B alignment. Rows are 396B-strided so quat addresses are only
// guaranteed 4B-aligned; amdgpu KMD runs SH_MEM_CONFIG.ALIGNMENT_MODE=UNALIGNED,
// so global_load_dwordx4 at dword alignment is handled by HW (may split lines).
__device__ __forceinline__ void ld4u(const float* __restrict__ p, float* q) {
  const float4 v = *reinterpret_cast<const float4*>(p);
  q[0] = v.x; q[1] = v.y; q[2] = v.z; q[3] = v.w;
}

__device__ __forceinline__ void quat2mat_s(const float* q, float s, float* R) {
  const float w = q[0], x = q[1], y = q[2], z = q[3];
  const float xx = s*x*x, yy = s*y*y, zz = s*z*z;
  const float xy = s*x*y, xz = s*x*z, yz = s*y*z;
  const float xw = s*x*w, yw = s*y*w, zw = s*z*w;
  R[0] = 1.0f - (yy+zz); R[1] = xy - zw;        R[2] = xz + yw;
  R[3] = xy + zw;        R[4] = 1.0f - (xx+zz); R[5] = yz - xw;
  R[6] = xz - yw;        R[7] = yz + xw;        R[8] = 1.0f - (xx+yy);
}

__device__ __forceinline__ void mm3(const float* A, const float* B, float* C) {
#pragma unroll
  for (int r = 0; r < 3; ++r) {
#pragma unroll
    for (int c = 0; c < 3; ++c) {
      C[3*r+c] = fmaf(A[3*r], B[c], fmaf(A[3*r+1], B[3+c], A[3*r+2]*B[6+c]));
    }
  }
}

// One fused pass: X-chain and Y-chain advance together in joint-index order
// (valid because topology[i] < i). Liveness analysis of index-order traversal
// shows <=3 ancestor states live at once -> 3 register slots (A=0,B=1,C=2).
// Carry only the translation DIFFERENCE D = gtrY - gtrX per slot:
//   D_child = D_parent + GY_p*tY[j] - GX_p*tX[j]
// which kills the gtrX[72] array and the separate MSE pass entirely.
__global__ __launch_bounds__(BLOCK, 2) void motion_loss_kernel(
    const float* __restrict__ Ym, const float* __restrict__ Xm,
    const float* __restrict__ Yt, const float* __restrict__ Xt,
    float* __restrict__ out) {
  const int tid = threadIdx.x;
  const size_t row = (size_t)blockIdx.x * BLOCK + tid;
  const int b = (int)(row / TT);                 // block lies in one batch (2048 % 128 == 0)
  const float* __restrict__ xr = Xm + row * ROWF;
  const float* __restrict__ yr = Ym + row * ROWF;
  const float* __restrict__ tX = Xt + (size_t)b * NJ * 3;   // uniform per block -> s_loads
  const float* __restrict__ tY = Yt + (size_t)b * NJ * 3;

  float GX[3][9], GY[3][9], D[3][3];
  float rot_acc = 0.0f, gtr_acc = 0.0f, pos_acc = 0.0f;

  // ---- joint 0 (root) ----
  {
    float xq[4], yq[4];
    ld4u(xr, xq); ld4u(yr, yq);
    const float qqx = xq[0]*xq[0] + xq[1]*xq[1] + xq[2]*xq[2] + xq[3]*xq[3];
    const float qqy = yq[0]*yq[0] + yq[1]*yq[1] + yq[2]*yq[2] + yq[3]*yq[3];
    const float ix = 1.0f / fmaxf(sqrtf(qqx), 1e-12f);
    const float iy = 1.0f / fmaxf(sqrtf(qqy), 1e-12f);
    const float r0 = yq[0]*iy - xq[0]*ix, r1 = yq[1]*iy - xq[1]*ix;
    const float r2 = yq[2]*iy - xq[2]*ix, r3 = yq[3]*iy - xq[3]*ix;
    rot_acc += r0*r0 + r1*r1 + r2*r2 + r3*r3;
    quat2mat_s(xq, 2.0f / qqx, GX[0]);
    quat2mat_s(yq, 2.0f / qqy, GY[0]);
    // pos at floats [96..98]: load [95..98] as one x4 (in-bounds, element 95 = quat 23 tail)
    float xp[4], yp[4];
    ld4u(xr + 95, xp); ld4u(yr + 95, yp);
    D[0][0] = yp[1] - xp[1]; D[0][1] = yp[2] - xp[2]; D[0][2] = yp[3] - xp[3];
    const float d2 = D[0][0]*D[0][0] + D[0][1]*D[0][1] + D[0][2]*D[0][2];
    gtr_acc += d2;     // root joint contributes to gtr MSE
    pos_acc = d2;      // and to the pos MSE term
  }

#define JSTEP(j, PS, NS) do {                                                  \
    float xq[4], yq[4];                                                        \
    ld4u(xr + 4*(j), xq); ld4u(yr + 4*(j), yq);                                \
    const float qqx = xq[0]*xq[0] + xq[1]*xq[1] + xq[2]*xq[2] + xq[3]*xq[3];   \
    const float qqy = yq[0]*yq[0] + yq[1]*yq[1] + yq[2]*yq[2] + yq[3]*yq[3];   \
    const float ix = 1.0f / fmaxf(sqrtf(qqx), 1e-12f);                         \
    const float iy = 1.0f / fmaxf(sqrtf(qqy), 1e-12f);                         \
    const float r0 = yq[0]*iy - xq[0]*ix, r1 = yq[1]*iy - xq[1]*ix;            \
    const float r2 = yq[2]*iy - xq[2]*ix, r3 = yq[3]*iy - xq[3]*ix;            \
    rot_acc += r0*r0 + r1*r1 + r2*r2 + r3*r3;                                  \
    const float tx0 = tX[3*(j)], tx1 = tX[3*(j)+1], tx2 = tX[3*(j)+2];         \
    const float ty0 = tY[3*(j)], ty1 = tY[3*(j)+1], ty2 = tY[3*(j)+2];         \
    const float vx0 = fmaf(GX[PS][0],tx0, fmaf(GX[PS][1],tx1, GX[PS][2]*tx2)); \
    const float vx1 = fmaf(GX[PS][3],tx0, fmaf(GX[PS][4],tx1, GX[PS][5]*tx2)); \
    const float vx2 = fmaf(GX[PS][6],tx0, fmaf(GX[PS][7],tx1, GX[PS][8]*tx2)); \
    const float vy0 = fmaf(GY[PS][0],ty0, fmaf(GY[PS][1],ty1, GY[PS][2]*ty2)); \
    const float vy1 = fmaf(GY[PS][3],ty0, fmaf(GY[PS][4],ty1, GY[PS][5]*ty2)); \
    const float vy2 = fmaf(GY[PS][6],ty0, fmaf(GY[PS][7],ty1, GY[PS][8]*ty2)); \
    const float d0 = D[PS][0] + (vy0 - vx0);                                   \
    const float d1 = D[PS][1] + (vy1 - vx1);                                   \
    const float d2 = D[PS][2] + (vy2 - vx2);                                   \
    gtr_acc += d0*d0 + d1*d1 + d2*d2;                                          \
    float RX[9], RY[9], GnX[9], GnY[9];                                        \
    quat2mat_s(xq, 2.0f / qqx, RX);                                            \
    quat2mat_s(yq, 2.0f / qqy, RY);                                            \
    mm3(GX[PS], RX, GnX);                                                      \
    mm3(GY[PS], RY, GnY);                                                      \
    _Pragma("unroll")                                                          \
    for (int k = 0; k < 9; ++k) { GX[NS][k] = GnX[k]; GY[NS][k] = GnY[k]; }    \
    D[NS][0] = d0; D[NS][1] = d1; D[NS][2] = d2;                               \
  } while (0)

  // Index-order walk of TOPOLOGY = [-1,0,0,0,1,2,3,4,5,6,7,8,9,9,9,12,13,14,16,17,18,19,20,21]
  // Slot schedule (parent-slot -> new-slot), verified against liveness:
  JSTEP( 1, 0, 1);  // p=0
  JSTEP( 2, 0, 2);  // p=0
  JSTEP( 3, 0, 0);  // p=0 (0 dead after: last child)
  JSTEP( 4, 1, 1);  // p=1
  JSTEP( 5, 2, 2);  // p=2
  JSTEP( 6, 0, 0);  // p=3
  JSTEP( 7, 1, 1);  // p=4
  JSTEP( 8, 2, 2);  // p=5
  JSTEP( 9, 0, 0);  // p=6
  JSTEP(10, 1, 1);  // p=7 (leaf)
  JSTEP(11, 2, 2);  // p=8 (leaf)
  JSTEP(12, 0, 1);  // p=9, B free
  JSTEP(13, 0, 2);  // p=9, C free
  JSTEP(14, 0, 0);  // p=9 (last child of 9)
  JSTEP(15, 1, 1);  // p=12 (leaf)
  JSTEP(16, 2, 2);  // p=13
  JSTEP(17, 0, 0);  // p=14
  JSTEP(18, 2, 2);  // p=16
  JSTEP(19, 0, 0);  // p=17
  JSTEP(20, 2, 2);  // p=18
  JSTEP(21, 0, 0);  // p=19
  JSTEP(22, 2, 2);  // p=20 (leaf)
  JSTEP(23, 0, 0);  // p=21 (leaf)
#undef JSTEP

  const float c_rot = 1.0f / ((float)NROWS * NJ * 4);   // B1 * mean over (bs,T,24,4)
  const float c_gtr = 2.5f / ((float)NROWS * NJ * 3);   // B2 * 2.5 * mean over (bs,T,24,3)
  const float c_pos = 1.0f / ((float)NROWS * 3);        // B2 * mean over (bs,T,3)
  float contrib = c_rot * rot_acc + c_gtr * gtr_acc + c_pos * pos_acc;
#pragma unroll
  for (int o = 32; o > 0; o >>= 1) contrib += __shfl_down(contrib, o, 64);
  if ((tid & 63) == 0) atomicAdd(out, contrib);
}

extern "C" void kernel_launch(void* const* d_in, const int* in_sizes, int n_in,
                              void* d_out, int out_size, void* d_ws, size_t ws_size,
                              hipStream_t stream) {
  const float* Ym = (const float*)d_in[0];
  const float* Xm = (const float*)d_in[1];
  const float* Yt = (const float*)d_in[2];
  const float* Xt = (const float*)d_in[3];
  float* out = (float*)d_out;
  hipMemsetAsync(out, 0, sizeof(float), stream);  // graph-capturable
  motion_loss_kernel<<<NROWS / BLOCK, BLOCK, 0, stream>>>(Ym, Xm, Yt, Xt, out);
}